// Round 1
// baseline (178.250 us; speedup 1.0000x reference)
//
#include <hip/hip_runtime.h>
#include <hip/hip_bf16.h>
#include <math.h>

// ---- problem constants ----
#define BATCH 16
#define CIN   128
#define COUT  128
#define HH    56
#define WW    56
#define SS    3136          // 56*56
#define RB    16            // bottleneck width
#define MOCH  256           // M*C_OUT
#define KKTOT 1152          // CIN*3*3
#define WDSZ  147456        // COUT*KKTOT
#define PROWS 58
#define PCOLS 64
#define XPAD_PER_C (PROWS*PCOLS)      // 3712
#define XPAD_PER_B (CIN*XPAD_PER_C)   // 475136

typedef __attribute__((ext_vector_type(8))) __bf16 bf16x8;
typedef __attribute__((ext_vector_type(4))) float  floatx4;

static __device__ __forceinline__ unsigned short f2bf(float f) {
  union { float f; unsigned u; } v; v.f = f;
  unsigned r = v.u + 0x7fffu + ((v.u >> 16) & 1u);   // RNE
  return (unsigned short)(r >> 16);
}

static __device__ __forceinline__ float waveReduceSum(float v) {
  #pragma unroll
  for (int off = 32; off > 0; off >>= 1) v += __shfl_xor(v, off, 64);
  return v;
}
static __device__ __forceinline__ float waveReduceMax(float v) {
  #pragma unroll
  for (int off = 32; off > 0; off >>= 1) v = fmaxf(v, __shfl_xor(v, off, 64));
  return v;
}

// K0: x (fp32, [b,c,56,56]) -> zero-padded bf16 [b,c,58,64]
__global__ void k0_pad(const float* __restrict__ x, unsigned short* __restrict__ xpad) {
  int gid = blockIdx.x * 256 + threadIdx.x;
  if (gid >= BATCH * XPAD_PER_B) return;
  int pcol = gid & 63;
  int rest = gid >> 6;
  int prow = rest % PROWS;
  int bc   = rest / PROWS;
  int y = prow - 1, xx = pcol - 1;
  unsigned short v = 0;
  if ((unsigned)y < 56u && (unsigned)xx < 56u)
    v = f2bf(x[(size_t)bc * SS + y * 56 + xx]);
  xpad[gid] = v;
}

// K1: mask[b,s] = sum_c x[b,c,s]*w_mask[c] + b_mask
__global__ void k1_mask(const float* __restrict__ x, const float* __restrict__ w_mask,
                        const float* __restrict__ b_mask, float* __restrict__ att) {
  int gid = blockIdx.x * 256 + threadIdx.x;   // 16*3136 = 50176 exact
  int b = gid / SS, s = gid - (gid / SS) * SS;
  const float* xb = x + (size_t)b * CIN * SS + s;
  float acc = b_mask[0];
  #pragma unroll 8
  for (int c = 0; c < CIN; c++) acc += xb[(size_t)c * SS] * w_mask[c];
  att[gid] = acc;
}

// K2: in-place softmax over s (3136) per batch
__global__ void k2_softmax(float* __restrict__ att) {
  int b = blockIdx.x, t = threadIdx.x;
  float* ab = att + b * SS;
  __shared__ float red[16];
  float m = -1e30f;
  for (int i = t; i < SS; i += 1024) m = fmaxf(m, ab[i]);
  m = waveReduceMax(m);
  if ((t & 63) == 0) red[t >> 6] = m;
  __syncthreads();
  float M = red[0];
  #pragma unroll
  for (int i = 1; i < 16; i++) M = fmaxf(M, red[i]);
  __syncthreads();   // everyone has read red before it is reused
  float sum = 0.f;
  for (int i = t; i < SS; i += 1024) { float e = expf(ab[i] - M); ab[i] = e; sum += e; }
  sum = waveReduceSum(sum);
  if ((t & 63) == 0) red[t >> 6] = sum;
  __syncthreads();
  float S = 0.f;
  #pragma unroll
  for (int i = 0; i < 16; i++) S += red[i];
  float inv = 1.0f / S;
  for (int i = t; i < SS; i += 1024) ab[i] *= inv;
}

// K3: ctx[b,c] = sum_s x[b,c,s]*att[b,s]
__global__ void k3_ctx(const float* __restrict__ x, const float* __restrict__ att,
                       float* __restrict__ ctx) {
  int c = blockIdx.x, b = blockIdx.y, t = threadIdx.x;
  const float* xb = x + ((size_t)b * CIN + c) * SS;
  const float* ab = att + b * SS;
  float acc = 0.f;
  for (int s = t; s < SS; s += 256) acc += xb[s] * ab[s];
  __shared__ float red[4];
  acc = waveReduceSum(acc);
  if ((t & 63) == 0) red[t >> 6] = acc;
  __syncthreads();
  if (t == 0) ctx[b * CIN + c] = red[0] + red[1] + red[2] + red[3];
}

// K4: bottleneck MLP: t=ctx@w1^T+b1; LN; relu; a=sigmoid(t@w2^T+b2)
__global__ void k4_transform(const float* __restrict__ ctx, const float* __restrict__ w1,
                             const float* __restrict__ b1, const float* __restrict__ ln_g,
                             const float* __restrict__ ln_b, const float* __restrict__ w2,
                             const float* __restrict__ b2, float* __restrict__ aout) {
  int b = blockIdx.x, t = threadIdx.x;   // 64 threads
  __shared__ float sc[128], st[16], sn[16];
  sc[t] = ctx[b * 128 + t];
  sc[t + 64] = ctx[b * 128 + t + 64];
  __syncthreads();
  if (t < 16) {
    float acc = b1[t];
    #pragma unroll 8
    for (int c = 0; c < 128; c++) acc += sc[c] * w1[t * 128 + c];
    st[t] = acc;
  }
  __syncthreads();
  float mu = 0.f, m2 = 0.f;
  #pragma unroll
  for (int r = 0; r < 16; r++) { mu += st[r]; m2 += st[r] * st[r]; }
  mu *= (1.f / 16.f); m2 *= (1.f / 16.f);
  float rstd = rsqrtf(m2 - mu * mu + 1e-5f);
  if (t < 16) {
    float v = (st[t] - mu) * rstd * ln_g[t] + ln_b[t];
    sn[t] = fmaxf(v, 0.f);
  }
  __syncthreads();
  #pragma unroll
  for (int i = 0; i < 4; i++) {
    int mo = t + 64 * i;
    float acc = b2[mo];
    #pragma unroll
    for (int r = 0; r < 16; r++) acc += sn[r] * w2[mo * 16 + r];
    aout[b * 256 + mo] = 1.f / (1.f + expf(-acc));
  }
}

// K5: per-sample conv weights: wd[b,j] = bf16(a[b, j/576]*w_fc[j] + b_fc[j])
__global__ void k5_wdgen(const float* __restrict__ a, const float* __restrict__ w_fc,
                         const float* __restrict__ b_fc, unsigned short* __restrict__ wd) {
  int j = blockIdx.x * 256 + threadIdx.x;  // 147456 exact
  int b = blockIdx.y;
  int g = j / 576;
  float v = a[b * 256 + g] * w_fc[j] + b_fc[j];
  wd[(size_t)b * WDSZ + j] = f2bf(v);
}

// K6: per-sample implicit-GEMM conv. Block = (row-pair y0, b), tile 128co x 128s
// (s: 2 rows of 56 = 112 valid + 16 pad cols). BK=64, 18 K-steps, no tails.
#define LDT 72   // LDS row stride in bf16 units (64 + 8 pad), keeps b128 reads 16B-aligned
__global__ __launch_bounds__(256) void k6_conv(const unsigned short* __restrict__ xpad,
                                               const unsigned short* __restrict__ wd,
                                               float* __restrict__ out) {
  __shared__ unsigned short As[128 * LDT];   // [co][k]
  __shared__ unsigned short Bs[128 * LDT];   // [s][k] (transposed patch tile)
  __shared__ int ktab[KKTOT];
  int t = threadIdx.x;
  int b = blockIdx.y;
  int y0 = blockIdx.x * 2;

  for (int e = t; e < KKTOT; e += 256) {
    int ci = e / 9, r9 = e - (e / 9) * 9;
    int kh = r9 / 3, kw = r9 - (r9 / 3) * 3;
    ktab[e] = ci * XPAD_PER_C + kh * PCOLS + kw;
  }

  // B-staging assignment: thread stages column s=t&127, k parity t>>7
  int sB = t & 127;
  int kpar = t >> 7;
  int srow = sB / 56;
  int scol = sB - srow * 56;
  if (srow >= 2) { srow = 0; scol = 0; }       // pad columns load dummy (never stored)
  const unsigned short* xb = xpad + (size_t)b * XPAD_PER_B + (y0 + srow) * PCOLS + scol;
  const unsigned short* wb = wd + (size_t)b * WDSZ;

  int lane = t & 63;
  int wave = t >> 6;
  int l15 = lane & 15;
  int quad = lane >> 4;
  int co_base = (wave & 1) * 64;
  int s_base  = (wave >> 1) * 64;

  floatx4 acc[4][4];
  floatx4 zero = {0.f, 0.f, 0.f, 0.f};
  #pragma unroll
  for (int i = 0; i < 4; i++)
    #pragma unroll
    for (int j = 0; j < 4; j++) acc[i][j] = zero;

  for (int k0 = 0; k0 < KKTOT; k0 += 64) {
    __syncthreads();   // previous iter's frag reads done before overwrite
    // stage A: 128co x 64k, 16B vector loads
    #pragma unroll
    for (int i = 0; i < 4; i++) {
      int e = t + 256 * i;
      int co = e >> 3, kc = e & 7;
      uint4 v = *reinterpret_cast<const uint4*>(wb + co * KKTOT + k0 + kc * 8);
      *reinterpret_cast<uint4*>(&As[co * LDT + kc * 8]) = v;
    }
    // stage B: gather im2col patches (2B each; ktab removes div/mod)
    #pragma unroll
    for (int p = 0; p < 32; p++) {
      int k = kpar + 2 * p;
      Bs[sB * LDT + k] = xb[ktab[k0 + k]];
    }
    __syncthreads();
    #pragma unroll
    for (int kk = 0; kk < 2; kk++) {
      bf16x8 af[4], bfr[4];
      #pragma unroll
      for (int i = 0; i < 4; i++)
        af[i] = *reinterpret_cast<const bf16x8*>(&As[(co_base + i * 16 + l15) * LDT + kk * 32 + quad * 8]);
      #pragma unroll
      for (int j = 0; j < 4; j++)
        bfr[j] = *reinterpret_cast<const bf16x8*>(&Bs[(s_base + j * 16 + l15) * LDT + kk * 32 + quad * 8]);
      #pragma unroll
      for (int i = 0; i < 4; i++)
        #pragma unroll
        for (int j = 0; j < 4; j++)
          acc[i][j] = __builtin_amdgcn_mfma_f32_16x16x32_bf16(af[i], bfr[j], acc[i][j], 0, 0, 0);
    }
  }

  // epilogue: D[co][s], col=lane&15, row=quad*4+r
  float* ob = out + (size_t)b * COUT * SS + y0 * 56;
  #pragma unroll
  for (int i = 0; i < 4; i++) {
    #pragma unroll
    for (int j = 0; j < 4; j++) {
      int sl = s_base + j * 16 + l15;
      if (sl < 112) {
        int row = (sl >= 56) ? 1 : 0;
        int col = sl - row * 56;
        #pragma unroll
        for (int r = 0; r < 4; r++) {
          int co = co_base + i * 16 + quad * 4 + r;
          ob[(size_t)co * SS + row * 56 + col] = acc[i][j][r];
        }
      }
    }
  }
}

extern "C" void kernel_launch(void* const* d_in, const int* in_sizes, int n_in,
                              void* d_out, int out_size, void* d_ws, size_t ws_size,
                              hipStream_t stream) {
  const float* x      = (const float*)d_in[0];
  const float* w_mask = (const float*)d_in[1];
  const float* b_mask = (const float*)d_in[2];
  const float* w1     = (const float*)d_in[3];
  const float* b1     = (const float*)d_in[4];
  const float* ln_g   = (const float*)d_in[5];
  const float* ln_b   = (const float*)d_in[6];
  const float* w2     = (const float*)d_in[7];
  const float* b2     = (const float*)d_in[8];
  const float* w_fc   = (const float*)d_in[9];
  const float* b_fc   = (const float*)d_in[10];
  float* out = (float*)d_out;

  char* ws = (char*)d_ws;
  unsigned short* xpad = (unsigned short*)(ws);              // 15,204,352 B
  unsigned short* wdw  = (unsigned short*)(ws + 15204352);   //  4,718,592 B
  float* att  = (float*)(ws + 19922944);                     //    200,704 B
  float* ctx  = (float*)(ws + 20123648);                     //      8,192 B
  float* aact = (float*)(ws + 20131840);                     //     16,384 B
  // total ws use: 20,148,224 B

  k0_pad      <<<dim3(29696),    dim3(256),  0, stream>>>(x, xpad);
  k1_mask     <<<dim3(196),      dim3(256),  0, stream>>>(x, w_mask, b_mask, att);
  k2_softmax  <<<dim3(16),       dim3(1024), 0, stream>>>(att);
  k3_ctx      <<<dim3(128, 16),  dim3(256),  0, stream>>>(x, att, ctx);
  k4_transform<<<dim3(16),       dim3(64),   0, stream>>>(ctx, w1, b1, ln_g, ln_b, w2, b2, aact);
  k5_wdgen    <<<dim3(576, 16),  dim3(256),  0, stream>>>(aact, w_fc, b_fc, wdw);
  k6_conv     <<<dim3(28, 16),   dim3(256),  0, stream>>>(xpad, wdw, out);
}

// Round 2
// 175.230 us; speedup vs baseline: 1.0172x; 1.0172x over previous
//
#include <hip/hip_runtime.h>
#include <hip/hip_bf16.h>
#include <math.h>

// ---- problem constants ----
#define BATCH 16
#define CIN   128
#define COUT  128
#define HH    56
#define WW    56
#define SS    3136          // 56*56
#define KKTOT 1152          // CIN*3*3
#define PROWS 58
#define PCOLS 64
#define XPAD_PER_C (PROWS*PCOLS)      // 3712
#define XPAD_PER_B (CIN*XPAD_PER_C)   // 475136
#define NKB   18            // K-steps (1152/64)
#define PANEL 8192          // shorts per K-panel (128co x 64k)

typedef __attribute__((ext_vector_type(8))) __bf16 bf16x8;
typedef __attribute__((ext_vector_type(4))) float  floatx4;

static __device__ __forceinline__ unsigned short f2bf(float f) {
  union { float f; unsigned u; } v; v.f = f;
  unsigned r = v.u + 0x7fffu + ((v.u >> 16) & 1u);   // RNE
  return (unsigned short)(r >> 16);
}

static __device__ __forceinline__ float waveReduceSum(float v) {
  #pragma unroll
  for (int off = 32; off > 0; off >>= 1) v += __shfl_xor(v, off, 64);
  return v;
}
static __device__ __forceinline__ float waveReduceMax(float v) {
  #pragma unroll
  for (int off = 32; off > 0; off >>= 1) v = fmaxf(v, __shfl_xor(v, off, 64));
  return v;
}

static __device__ __forceinline__ void load_lds16(const void* g, void* l) {
  __builtin_amdgcn_global_load_lds(
      (const __attribute__((address_space(1))) void*)g,
      (__attribute__((address_space(3))) void*)l, 16, 0, 0);
}

// K0: x (fp32, [b,c,56,56]) -> zero-padded bf16 [b,c,58,64]
__global__ void k0_pad(const float* __restrict__ x, unsigned short* __restrict__ xpad) {
  int gid = blockIdx.x * 256 + threadIdx.x;
  if (gid >= BATCH * XPAD_PER_B) return;
  int pcol = gid & 63;
  int rest = gid >> 6;
  int prow = rest % PROWS;
  int bc   = rest / PROWS;
  int y = prow - 1, xx = pcol - 1;
  unsigned short v = 0;
  if ((unsigned)y < 56u && (unsigned)xx < 56u)
    v = f2bf(x[(size_t)bc * SS + y * 56 + xx]);
  xpad[gid] = v;
}

// K1: mask[b,s] = sum_c x[b,c,s]*w_mask[c] + b_mask  (784 blocks x 64)
__global__ void k1_mask(const float* __restrict__ x, const float* __restrict__ w_mask,
                        const float* __restrict__ b_mask, float* __restrict__ att) {
  int gid = blockIdx.x * 64 + threadIdx.x;   // 50176 exact
  int b = gid / SS, s = gid - (gid / SS) * SS;
  const float* xb = x + (size_t)b * CIN * SS + s;
  float acc = b_mask[0];
  #pragma unroll 8
  for (int c = 0; c < CIN; c++) acc += xb[(size_t)c * SS] * w_mask[c];
  att[gid] = acc;
}

// K2: att <- exp(att - max), zinv[b] = 1/sum (k3 applies the normalization)
__global__ void k2_softmax(float* __restrict__ att, float* __restrict__ zinv) {
  int b = blockIdx.x, t = threadIdx.x;
  float* ab = att + b * SS;
  __shared__ float red[16];
  float m = -1e30f;
  for (int i = t; i < SS; i += 1024) m = fmaxf(m, ab[i]);
  m = waveReduceMax(m);
  if ((t & 63) == 0) red[t >> 6] = m;
  __syncthreads();
  float M = red[0];
  #pragma unroll
  for (int i = 1; i < 16; i++) M = fmaxf(M, red[i]);
  __syncthreads();
  float sum = 0.f;
  for (int i = t; i < SS; i += 1024) { float e = expf(ab[i] - M); ab[i] = e; sum += e; }
  sum = waveReduceSum(sum);
  if ((t & 63) == 0) red[t >> 6] = sum;
  __syncthreads();
  if (t == 0) {
    float S = 0.f;
    #pragma unroll
    for (int i = 0; i < 16; i++) S += red[i];
    zinv[b] = 1.0f / S;
  }
}

// K3: ctx[b,c] = zinv[b] * sum_s x[b,c,s]*exp_att[b,s]   (float4 loads)
__global__ void k3_ctx(const float* __restrict__ x, const float* __restrict__ att,
                       const float* __restrict__ zinv, float* __restrict__ ctx) {
  int c = blockIdx.x, b = blockIdx.y, t = threadIdx.x;
  const float4* xb = (const float4*)(x + ((size_t)b * CIN + c) * SS);
  const float4* ab = (const float4*)(att + b * SS);
  float acc = 0.f;
  for (int i = t; i < 784; i += 256) {            // 3136/4
    float4 xv = xb[i], av = ab[i];
    acc += xv.x * av.x + xv.y * av.y + xv.z * av.z + xv.w * av.w;
  }
  __shared__ float red[4];
  acc = waveReduceSum(acc);
  if ((t & 63) == 0) red[t >> 6] = acc;
  __syncthreads();
  if (t == 0) ctx[b * CIN + c] = (red[0] + red[1] + red[2] + red[3]) * zinv[b];
}

// K4: bottleneck MLP: t=ctx@w1^T+b1; LN; relu; a=sigmoid(t@w2^T+b2)
__global__ void k4_transform(const float* __restrict__ ctx, const float* __restrict__ w1,
                             const float* __restrict__ b1, const float* __restrict__ ln_g,
                             const float* __restrict__ ln_b, const float* __restrict__ w2,
                             const float* __restrict__ b2, float* __restrict__ aout) {
  int b = blockIdx.x, t = threadIdx.x;   // 64 threads
  __shared__ float sc[128], st[16], sn[16];
  sc[t] = ctx[b * 128 + t];
  sc[t + 64] = ctx[b * 128 + t + 64];
  __syncthreads();
  if (t < 16) {
    float acc = b1[t];
    #pragma unroll 8
    for (int c = 0; c < 128; c++) acc += sc[c] * w1[t * 128 + c];
    st[t] = acc;
  }
  __syncthreads();
  float mu = 0.f, m2 = 0.f;
  #pragma unroll
  for (int r = 0; r < 16; r++) { mu += st[r]; m2 += st[r] * st[r]; }
  mu *= (1.f / 16.f); m2 *= (1.f / 16.f);
  float rstd = rsqrtf(m2 - mu * mu + 1e-5f);
  if (t < 16) {
    float v = (st[t] - mu) * rstd * ln_g[t] + ln_b[t];
    sn[t] = fmaxf(v, 0.f);
  }
  __syncthreads();
  #pragma unroll
  for (int i = 0; i < 4; i++) {
    int mo = t + 64 * i;
    float acc = b2[mo];
    #pragma unroll
    for (int r = 0; r < 16; r++) acc += sn[r] * w2[mo * 16 + r];
    aout[b * 256 + mo] = 1.f / (1.f + expf(-acc));
  }
}

// K5: generate per-sample conv weights as 18 K-panels [kb][co][kq], kq XOR-swizzled
// at 16B-chunk granularity so k6's A-fragment LDS reads are bank-conflict-free.
// K-ordering: k = khw*128 + ci (spatial-major), khw = kh*3+kw.
__global__ void k5_wdgen(const float* __restrict__ a, const float* __restrict__ w_fc,
                         const float* __restrict__ b_fc, unsigned short* __restrict__ wd) {
  int e = blockIdx.x * 256 + threadIdx.x;  // 147456 per sample
  int b = blockIdx.y;
  int kb = e >> 13;           // panel 0..17
  int r  = e & 8191;
  int co = r >> 6;
  int kq = r & 63;
  int khw = kb >> 1;
  int ci  = ((kb & 1) << 6) + kq;
  int rem = ci * 9 + khw;
  int j   = co * 1152 + rem;                 // index into w_fc/b_fc ([co][ci][kh][kw])
  int g   = co * 2 + (rem >= 576 ? 1 : 0);   // grouped-conv group = j/576
  float v = a[b * 256 + g] * w_fc[j] + b_fc[j];
  int pos = (((kq >> 3) ^ (co & 7)) << 3) | (kq & 7);
  wd[((size_t)(b * NKB + kb) * 128 + co) * 64 + pos] = f2bf(v);
}

// K6: per-sample implicit-GEMM conv. Block = (row-pair y0, b), tile 128co x 128s.
// A staged via global_load_lds from contiguous pre-swizzled panels; B staged as
// 8 coalesced 2B gathers -> 1 ds_write_b128 (conflict-free at LDT=72).
#define LDTB 72
__global__ __launch_bounds__(256) void k6_conv(const unsigned short* __restrict__ xpad,
                                               const unsigned short* __restrict__ wd,
                                               float* __restrict__ out) {
  __shared__ __align__(16) unsigned short As[128 * 64];    // 16KB, swizzled panel
  __shared__ __align__(16) unsigned short Bs[128 * LDTB];  // 18KB
  int t = threadIdx.x;
  int b = blockIdx.y;
  int y0 = blockIdx.x * 2;

  // B-staging: thread stages s-column sB, ci-chunks {2q + h}
  int sB = t & 127;
  int h  = t >> 7;
  int srow = sB / 56;
  int scol = sB - srow * 56;
  if (srow >= 2) { srow = 0; scol = 0; }       // pad columns: dummy (never stored)
  const unsigned short* xb = xpad + (size_t)b * XPAD_PER_B + (y0 + srow) * PCOLS + scol;
  const unsigned short* wp = wd + (size_t)b * (NKB * PANEL);

  int lane = t & 63;
  int wave = t >> 6;
  int l15  = lane & 15;
  int quad = lane >> 4;
  int x7   = l15 & 7;          // co&7 for this lane's A rows
  int co_base = (wave & 1) * 64;
  int s_base  = (wave >> 1) * 64;

  floatx4 acc[4][4];
  floatx4 zero = {0.f, 0.f, 0.f, 0.f};
  #pragma unroll
  for (int i = 0; i < 4; i++)
    #pragma unroll
    for (int j = 0; j < 4; j++) acc[i][j] = zero;

  #pragma unroll
  for (int kb = 0; kb < NKB; kb++) {
    __syncthreads();   // previous iter's frag reads done before overwrite
    // ---- stage A: 16KB contiguous panel -> LDS via async DMA ----
    const unsigned short* asrc = wp + kb * PANEL;
    #pragma unroll
    for (int i = 0; i < 4; i++) {
      int chunk = wave * 256 + i * 64 + lane;                 // 16B chunk id
      load_lds16(asrc + chunk * 8, &As[(wave * 256 + i * 64) * 8]);
    }
    // ---- stage B: gather 8 coalesced shorts -> one b128 write, x4 ----
    {
      int khw = kb >> 1, kh = khw / 3, kw = khw - (khw / 3) * 3;
      const unsigned short* xrow = xb + (size_t)((kb & 1) << 6) * XPAD_PER_C + kh * PCOLS + kw;
      #pragma unroll
      for (int q = 0; q < 4; q++) {
        int c = 2 * q + h;
        bf16x8 tmp;
        #pragma unroll
        for (int j = 0; j < 8; j++)
          ((unsigned short*)&tmp)[j] = xrow[(size_t)(c * 8 + j) * XPAD_PER_C];
        *reinterpret_cast<bf16x8*>(&Bs[sB * LDTB + c * 8]) = tmp;
      }
    }
    __syncthreads();
    // ---- inner MFMA ----
    #pragma unroll
    for (int kk = 0; kk < 2; kk++) {
      bf16x8 af[4], bfr[4];
      #pragma unroll
      for (int i = 0; i < 4; i++) {
        int co = co_base + i * 16 + l15;
        int pc = (kk * 4 + quad) ^ x7;
        af[i] = *reinterpret_cast<const bf16x8*>(&As[co * 64 + pc * 8]);
      }
      #pragma unroll
      for (int j = 0; j < 4; j++)
        bfr[j] = *reinterpret_cast<const bf16x8*>(&Bs[(s_base + j * 16 + l15) * LDTB + kk * 32 + quad * 8]);
      #pragma unroll
      for (int i = 0; i < 4; i++)
        #pragma unroll
        for (int j = 0; j < 4; j++)
          acc[i][j] = __builtin_amdgcn_mfma_f32_16x16x32_bf16(af[i], bfr[j], acc[i][j], 0, 0, 0);
    }
  }

  // epilogue: D[co][s], col=lane&15 -> s, row=quad*4+r -> co
  float* ob = out + (size_t)b * COUT * SS + y0 * 56;
  #pragma unroll
  for (int i = 0; i < 4; i++) {
    #pragma unroll
    for (int j = 0; j < 4; j++) {
      int sl = s_base + j * 16 + l15;
      if (sl < 112) {
        int row = (sl >= 56) ? 1 : 0;
        int col = sl - row * 56;
        #pragma unroll
        for (int r = 0; r < 4; r++) {
          int co = co_base + i * 16 + quad * 4 + r;
          ob[(size_t)co * SS + row * 56 + col] = acc[i][j][r];
        }
      }
    }
  }
}

extern "C" void kernel_launch(void* const* d_in, const int* in_sizes, int n_in,
                              void* d_out, int out_size, void* d_ws, size_t ws_size,
                              hipStream_t stream) {
  const float* x      = (const float*)d_in[0];
  const float* w_mask = (const float*)d_in[1];
  const float* b_mask = (const float*)d_in[2];
  const float* w1     = (const float*)d_in[3];
  const float* b1     = (const float*)d_in[4];
  const float* ln_g   = (const float*)d_in[5];
  const float* ln_b   = (const float*)d_in[6];
  const float* w2     = (const float*)d_in[7];
  const float* b2     = (const float*)d_in[8];
  const float* w_fc   = (const float*)d_in[9];
  const float* b_fc   = (const float*)d_in[10];
  float* out = (float*)d_out;

  char* ws = (char*)d_ws;
  unsigned short* xpad = (unsigned short*)(ws);              // 15,204,352 B
  unsigned short* wdw  = (unsigned short*)(ws + 15204352);   //  4,718,592 B
  float* att  = (float*)(ws + 19922944);                     //    200,704 B
  float* ctx  = (float*)(ws + 20123648);                     //      8,192 B
  float* aact = (float*)(ws + 20131840);                     //     16,384 B
  float* zinv = (float*)(ws + 20148224);                     //         64 B

  k0_pad      <<<dim3(29696),    dim3(256),  0, stream>>>(x, xpad);
  k1_mask     <<<dim3(784),      dim3(64),   0, stream>>>(x, w_mask, b_mask, att);
  k2_softmax  <<<dim3(16),       dim3(1024), 0, stream>>>(att, zinv);
  k3_ctx      <<<dim3(128, 16),  dim3(256),  0, stream>>>(x, att, zinv, ctx);
  k4_transform<<<dim3(16),       dim3(64),   0, stream>>>(ctx, w1, b1, ln_g, ln_b, w2, b2, aact);
  k5_wdgen    <<<dim3(576, 16),  dim3(256),  0, stream>>>(aact, w_fc, b_fc, wdw);
  k6_conv     <<<dim3(28, 16),   dim3(256),  0, stream>>>(xpad, wdw, out);
}

// Round 3
// 142.533 us; speedup vs baseline: 1.2506x; 1.2294x over previous
//
#include <hip/hip_runtime.h>
#include <hip/hip_bf16.h>
#include <math.h>

// ---- problem constants ----
#define BATCH 16
#define CIN   128
#define COUT  128
#define SS    3136          // 56*56
#define KKTOT 1152          // CIN*3*3
#define XT_ROW 8192         // shorts per padded row: 64 pcol * 128 ci
#define XT_PER_B (58*XT_ROW)
#define NKB   18

typedef __attribute__((ext_vector_type(8))) __bf16 bf16x8;
typedef __attribute__((ext_vector_type(4))) float  floatx4;

static __device__ __forceinline__ unsigned short f2bf(float f) {
  union { float f; unsigned u; } v; v.f = f;
  unsigned r = v.u + 0x7fffu + ((v.u >> 16) & 1u);   // RNE
  return (unsigned short)(r >> 16);
}
static __device__ __forceinline__ float bf2f(unsigned short u) {
  union { unsigned u; float f; } v; v.u = ((unsigned)u) << 16; return v.f;
}

static __device__ __forceinline__ float waveReduceSum(float v) {
  #pragma unroll
  for (int off = 32; off > 0; off >>= 1) v += __shfl_xor(v, off, 64);
  return v;
}
static __device__ __forceinline__ float waveReduceMax(float v) {
  #pragma unroll
  for (int off = 32; off > 0; off >>= 1) v = fmaxf(v, __shfl_xor(v, off, 64));
  return v;
}

static __device__ __forceinline__ void load_lds16(const void* g, void* l) {
  __builtin_amdgcn_global_load_lds(
      (const __attribute__((address_space(1))) void*)g,
      (__attribute__((address_space(3))) void*)l, 16, 0, 0);
}

// K0: fused pad+transpose to NHWC bf16 AND attention-mask row.
// grid (58, 16), block 256. xT[b][prow][pcol][ci]; att[b][y*56+x].
__global__ void k0_padT(const float* __restrict__ x, const float* __restrict__ w_mask,
                        const float* __restrict__ b_mask,
                        unsigned short* __restrict__ xT, float* __restrict__ att) {
  int b = blockIdx.y, prow = blockIdx.x, t = threadIdx.x;
  int y = prow - 1;
  __shared__ unsigned short sx[128 * 58];   // row stride 58 (odd word-stride -> spread banks)
  __shared__ float swm[128];
  __shared__ float red[4 * 56];
  bool rowvalid = ((unsigned)y < 56u);
  if (t < 128) swm[t] = w_mask[t];
  if (rowvalid) {
    int ci = t >> 1, h = t & 1;
    const float* src = x + (size_t)(b * 128 + ci) * SS + y * 56 + h * 28;
    #pragma unroll
    for (int c = 0; c < 28; c++) sx[ci * 58 + h * 28 + c] = f2bf(src[c]);
  } else {
    for (int i = t; i < 128 * 58; i += 256) sx[i] = 0;
  }
  __syncthreads();
  if (rowvalid && t < 224) {
    int xx = t % 56, g = t / 56;
    float acc = 0.f;
    #pragma unroll
    for (int k = 0; k < 32; k++) {
      int ci = g * 32 + k;
      acc += bf2f(sx[ci * 58 + xx]) * swm[ci];
    }
    red[g * 56 + xx] = acc;
  }
  __syncthreads();
  if (rowvalid && t < 56)
    att[b * SS + y * 56 + t] = red[t] + red[56 + t] + red[112 + t] + red[168 + t] + b_mask[0];
  // NHWC write: thread t -> pcol = t>>2, ci block = (t&3)*32, 64B contiguous
  int pcol = t >> 2, cig = t & 3;
  int xx = pcol - 1;
  bool colv = rowvalid && ((unsigned)xx < 56u);
  unsigned short tmp[32];
  #pragma unroll
  for (int i = 0; i < 32; i++)
    tmp[i] = colv ? sx[(cig * 32 + i) * 58 + xx] : (unsigned short)0;
  unsigned short* dst = xT + ((size_t)(b * 58 + prow) * 64 + pcol) * 128 + cig * 32;
  #pragma unroll
  for (int q = 0; q < 4; q++)
    *reinterpret_cast<uint4*>(dst + q * 8) = *reinterpret_cast<const uint4*>(tmp + q * 8);
}

// K2: att <- exp(att - max), zinv[b] = 1/sum
__global__ void k2_softmax(float* __restrict__ att, float* __restrict__ zinv) {
  int b = blockIdx.x, t = threadIdx.x;
  float* ab = att + b * SS;
  __shared__ float red[16];
  float m = -1e30f;
  for (int i = t; i < SS; i += 1024) m = fmaxf(m, ab[i]);
  m = waveReduceMax(m);
  if ((t & 63) == 0) red[t >> 6] = m;
  __syncthreads();
  float M = red[0];
  #pragma unroll
  for (int i = 1; i < 16; i++) M = fmaxf(M, red[i]);
  __syncthreads();
  float sum = 0.f;
  for (int i = t; i < SS; i += 1024) { float e = expf(ab[i] - M); ab[i] = e; sum += e; }
  sum = waveReduceSum(sum);
  if ((t & 63) == 0) red[t >> 6] = sum;
  __syncthreads();
  if (t == 0) {
    float S = 0.f;
    #pragma unroll
    for (int i = 0; i < 16; i++) S += red[i];
    zinv[b] = 1.0f / S;
  }
}

// K3: ctx[b,c] = zinv[b] * sum_s x[b,c,s]*exp_att[b,s]
__global__ void k3_ctx(const float* __restrict__ x, const float* __restrict__ att,
                       const float* __restrict__ zinv, float* __restrict__ ctx) {
  int c = blockIdx.x, b = blockIdx.y, t = threadIdx.x;
  const float4* xb = (const float4*)(x + ((size_t)b * CIN + c) * SS);
  const float4* ab = (const float4*)(att + b * SS);
  float acc = 0.f;
  for (int i = t; i < 784; i += 256) {
    float4 xv = xb[i], av = ab[i];
    acc += xv.x * av.x + xv.y * av.y + xv.z * av.z + xv.w * av.w;
  }
  __shared__ float red[4];
  acc = waveReduceSum(acc);
  if ((t & 63) == 0) red[t >> 6] = acc;
  __syncthreads();
  if (t == 0) ctx[b * CIN + c] = (red[0] + red[1] + red[2] + red[3]) * zinv[b];
}

// K4: bottleneck MLP
__global__ void k4_transform(const float* __restrict__ ctx, const float* __restrict__ w1,
                             const float* __restrict__ b1, const float* __restrict__ ln_g,
                             const float* __restrict__ ln_b, const float* __restrict__ w2,
                             const float* __restrict__ b2, float* __restrict__ aout) {
  int b = blockIdx.x, t = threadIdx.x;   // 64 threads
  __shared__ float sc[128], st[16], sn[16];
  sc[t] = ctx[b * 128 + t];
  sc[t + 64] = ctx[b * 128 + t + 64];
  __syncthreads();
  if (t < 16) {
    float acc = b1[t];
    #pragma unroll 8
    for (int c = 0; c < 128; c++) acc += sc[c] * w1[t * 128 + c];
    st[t] = acc;
  }
  __syncthreads();
  float mu = 0.f, m2 = 0.f;
  #pragma unroll
  for (int r = 0; r < 16; r++) { mu += st[r]; m2 += st[r] * st[r]; }
  mu *= (1.f / 16.f); m2 *= (1.f / 16.f);
  float rstd = rsqrtf(m2 - mu * mu + 1e-5f);
  if (t < 16) {
    float v = (st[t] - mu) * rstd * ln_g[t] + ln_b[t];
    sn[t] = fmaxf(v, 0.f);
  }
  __syncthreads();
  #pragma unroll
  for (int i = 0; i < 4; i++) {
    int mo = t + 64 * i;
    float acc = b2[mo];
    #pragma unroll
    for (int r = 0; r < 16; r++) acc += sn[r] * w2[mo * 16 + r];
    aout[b * 256 + mo] = 1.f / (1.f + expf(-acc));
  }
}

// K5: wd[b][co][kb][kq(swizzled)] ; K-order within step kb: ci=(kb&1)*64+kq, khw=kb>>1.
// Coalesced w_fc/b_fc reads (block = one co row, 1152 contiguous), contiguous writes.
__global__ void k5_wdgen(const float* __restrict__ a, const float* __restrict__ w_fc,
                         const float* __restrict__ b_fc, unsigned short* __restrict__ wd) {
  int co = blockIdx.x, b = blockIdx.y, t = threadIdx.x;   // 128 threads
  float a0 = a[b * 256 + 2 * co], a1 = a[b * 256 + 2 * co + 1];
  const float* wrow = w_fc + co * 1152;
  const float* brow = b_fc + co * 1152;
  unsigned short* drow = wd + (size_t)(b * 128 + co) * 1152;
  #pragma unroll
  for (int r = 0; r < 9; r++) {
    int e = t + 128 * r;
    int ci = e / 9, khw = e - (e / 9) * 9;
    float v = (ci < 64 ? a0 : a1) * wrow[e] + brow[e];
    int kb = khw * 2 + (ci >> 6);
    int kq = ci & 63;
    int pos = (((kq >> 3) ^ (co & 7)) << 3) | (kq & 7);
    drow[kb * 64 + pos] = f2bf(v);
  }
}

// K6: implicit-GEMM conv, 512 threads, tile 128co x 128s (2 out rows),
// both operands staged via global_load_lds (A: pre-swizzled weight rows,
// B: NHWC rows with source-permuted XOR swizzle). acc[4][2] per wave.
__global__ __launch_bounds__(512, 4) void k6_conv(const unsigned short* __restrict__ xT,
                                                  const unsigned short* __restrict__ wd,
                                                  float* __restrict__ out) {
  __shared__ __align__(16) unsigned short As[8192];   // [co128][kq64]
  __shared__ __align__(16) unsigned short Bs[8192];   // [s128][kq64]
  int t = threadIdx.x;
  int b = blockIdx.y, y0 = blockIdx.x * 2;
  int wave = t >> 6, lane = t & 63, l15 = lane & 15, quad = lane >> 4;
  int x7 = lane & 7;
  const unsigned short* wp  = wd + (size_t)b * (128 * 1152);
  const unsigned short* xTb = xT + (size_t)b * XT_PER_B;

  // DMA chunk ids (16B units): this thread covers ch0, ch1 of 1024
  int ch0 = wave * 128 + lane, ch1 = ch0 + 64;
  int offA0 = (ch0 >> 3) * 1152 + (ch0 & 7) * 8;      // + kb*64 per step
  int offA1 = (ch1 >> 3) * 1152 + (ch1 & 7) * 8;
  int s0 = ch0 >> 3, s1 = ch1 >> 3;
  int c_ = lane & 7;
  int sr0 = s0 / 56, sc0 = s0 - sr0 * 56; if (sr0 >= 2) { sr0 = 0; sc0 = 0; }
  int sr1 = s1 / 56, sc1 = s1 - sr1 * 56; if (sr1 >= 2) { sr1 = 0; sc1 = 0; }
  int offB0 = (y0 + sr0) * XT_ROW + sc0 * 128 + (c_ ^ (s0 & 7)) * 8;
  int offB1 = (y0 + sr1) * XT_ROW + sc1 * 128 + (c_ ^ (s1 & 7)) * 8;
  unsigned short* dA0 = &As[wave * 1024];
  unsigned short* dA1 = &As[wave * 1024 + 512];
  unsigned short* dB0 = &Bs[wave * 1024];
  unsigned short* dB1 = &Bs[wave * 1024 + 512];

  int s_base = (wave & 3) * 32;
  int co_b   = (wave >> 2) * 64;

  floatx4 acc[4][2];
  floatx4 zero = {0.f, 0.f, 0.f, 0.f};
  #pragma unroll
  for (int i = 0; i < 4; i++)
    #pragma unroll
    for (int j = 0; j < 2; j++) acc[i][j] = zero;

  for (int kb = 0; kb < NKB; kb++) {
    int khw = kb >> 1;
    int kh = khw / 3;
    int kw = khw - kh * 3;
    int dB = kh * XT_ROW + kw * 128 + ((kb & 1) << 6);
    int dA = kb * 64;
    __syncthreads();                      // prior frag reads complete
    load_lds16(wp + offA0 + dA, dA0);
    load_lds16(wp + offA1 + dA, dA1);
    load_lds16(xTb + offB0 + dB, dB0);
    load_lds16(xTb + offB1 + dB, dB1);
    __syncthreads();                      // DMA drained (vmcnt(0) at barrier)
    #pragma unroll
    for (int kk = 0; kk < 2; kk++) {
      bf16x8 af[4], bfr[2];
      int pc = ((kk * 4 + quad) ^ x7) << 3;
      #pragma unroll
      for (int i = 0; i < 4; i++)
        af[i] = *reinterpret_cast<const bf16x8*>(&As[(co_b + i * 16 + l15) * 64 + pc]);
      #pragma unroll
      for (int j = 0; j < 2; j++)
        bfr[j] = *reinterpret_cast<const bf16x8*>(&Bs[(s_base + j * 16 + l15) * 64 + pc]);
      #pragma unroll
      for (int i = 0; i < 4; i++)
        #pragma unroll
        for (int j = 0; j < 2; j++)
          acc[i][j] = __builtin_amdgcn_mfma_f32_16x16x32_bf16(af[i], bfr[j], acc[i][j], 0, 0, 0);
    }
  }

  // epilogue: D col (l15) -> s, row (quad*4+r) -> co
  float* ob = out + (size_t)b * COUT * SS + y0 * 56;
  #pragma unroll
  for (int i = 0; i < 4; i++) {
    #pragma unroll
    for (int j = 0; j < 2; j++) {
      int sl = s_base + j * 16 + l15;
      if (sl < 112) {
        int row = (sl >= 56) ? 1 : 0;
        int col = sl - row * 56;
        #pragma unroll
        for (int r = 0; r < 4; r++) {
          int co = co_b + i * 16 + quad * 4 + r;
          ob[(size_t)co * SS + row * 56 + col] = acc[i][j][r];
        }
      }
    }
  }
}

extern "C" void kernel_launch(void* const* d_in, const int* in_sizes, int n_in,
                              void* d_out, int out_size, void* d_ws, size_t ws_size,
                              hipStream_t stream) {
  const float* x      = (const float*)d_in[0];
  const float* w_mask = (const float*)d_in[1];
  const float* b_mask = (const float*)d_in[2];
  const float* w1     = (const float*)d_in[3];
  const float* b1     = (const float*)d_in[4];
  const float* ln_g   = (const float*)d_in[5];
  const float* ln_b   = (const float*)d_in[6];
  const float* w2     = (const float*)d_in[7];
  const float* b2     = (const float*)d_in[8];
  const float* w_fc   = (const float*)d_in[9];
  const float* b_fc   = (const float*)d_in[10];
  float* out = (float*)d_out;

  char* ws = (char*)d_ws;
  unsigned short* xT  = (unsigned short*)(ws);               // 15,204,352 B
  unsigned short* wdw = (unsigned short*)(ws + 15204352);    //  4,718,592 B
  float* att  = (float*)(ws + 19922944);                     //    200,704 B
  float* ctx  = (float*)(ws + 20123648);                     //      8,192 B
  float* aact = (float*)(ws + 20131840);                     //     16,384 B
  float* zinv = (float*)(ws + 20148224);                     //         64 B

  k0_padT     <<<dim3(58, 16),   dim3(256),  0, stream>>>(x, w_mask, b_mask, xT, att);
  k2_softmax  <<<dim3(16),       dim3(1024), 0, stream>>>(att, zinv);
  k3_ctx      <<<dim3(128, 16),  dim3(256),  0, stream>>>(x, att, zinv, ctx);
  k4_transform<<<dim3(16),       dim3(64),   0, stream>>>(ctx, w1, b1, ln_g, ln_b, w2, b2, aact);
  k5_wdgen    <<<dim3(128, 16),  dim3(128),  0, stream>>>(aact, w_fc, b_fc, wdw);
  k6_conv     <<<dim3(28, 16),   dim3(512),  0, stream>>>(xT, wdw, out);
}